// Round 11
// baseline (691.332 us; speedup 1.0000x reference)
//
#include <hip/hip_runtime.h>

#define B_   4
#define T_   2048
#define BT_  8192
#define INL  15
#define DM   256
#define DI   512
#define DX   1024
#define DS_  16
#define DR_  16
#define NO_  48
#define NL   4
#define NC_  128
#define LCH  16

typedef short bf16x8 __attribute__((ext_vector_type(8)));
typedef float f32x4  __attribute__((ext_vector_type(4)));

__device__ __forceinline__ float sigmoidf_(float x){ return 1.f/(1.f+__expf(-x)); }

__device__ __forceinline__ unsigned short f2bf(float x){
    union { float f; unsigned u; } v; v.f = x;
    unsigned r = (v.u + 0x7FFFu + ((v.u >> 16) & 1u)) >> 16;
    return (unsigned short)r;
}
__device__ __forceinline__ float bf2f(unsigned short h){
    union { unsigned u; float f; } v; v.u = ((unsigned)h) << 16;
    return v.f;
}
__device__ __forceinline__ unsigned packbf(float x){
    unsigned short hh = f2bf(x);
    unsigned short ll = f2bf(x - bf2f(hh));
    return (unsigned)hh | ((unsigned)ll << 16);
}

__device__ __forceinline__ void ld16(const float* __restrict__ p, float* v){
    const float4* q = (const float4*)p;
    float4 x0=q[0],x1=q[1],x2=q[2],x3=q[3];
    v[0]=x0.x; v[1]=x0.y; v[2]=x0.z; v[3]=x0.w;
    v[4]=x1.x; v[5]=x1.y; v[6]=x1.z; v[7]=x1.w;
    v[8]=x2.x; v[9]=x2.y; v[10]=x2.z; v[11]=x2.w;
    v[12]=x3.x; v[13]=x3.y; v[14]=x3.z; v[15]=x3.w;
}
__device__ __forceinline__ void st16(float* __restrict__ p, const float* v){
    float4* q = (float4*)p;
    q[0] = make_float4(v[0],v[1],v[2],v[3]);
    q[1] = make_float4(v[4],v[5],v[6],v[7]);
    q[2] = make_float4(v[8],v[9],v[10],v[11]);
    q[3] = make_float4(v[12],v[13],v[14],v[15]);
}

// convert fp32 array -> bf16 hi/lo split
__global__ void k_cvtW(const float* __restrict__ W, unsigned short* __restrict__ hi,
                       unsigned short* __restrict__ lo, int n4){
    int g = blockIdx.x*256 + threadIdx.x;
    if(g >= n4) return;
    float4 v = ((const float4*)W)[g];
    ushort4 h, l;
    h.x = f2bf(v.x); l.x = f2bf(v.x - bf2f(h.x));
    h.y = f2bf(v.y); l.y = f2bf(v.y - bf2f(h.y));
    h.z = f2bf(v.z); l.z = f2bf(v.z - bf2f(h.z));
    h.w = f2bf(v.w); l.w = f2bf(v.w - bf2f(h.w));
    ((ushort4*)hi)[g] = h;
    ((ushort4*)lo)[g] = l;
}

// h[bt][m] = sum_k x[bt][k] * in_W[m][k]
__global__ void k_ingemm(const float* __restrict__ x, const float* __restrict__ W,
                         float* __restrict__ h){
    int g  = blockIdx.x*256 + threadIdx.x;
    int bt = g >> 8, m = g & 255;
    const float* xr = x + bt*INL;
    const float* wr = W + m*INL;
    float acc = 0.f;
#pragma unroll
    for(int k=0;k<INL;k++) acc += xr[k]*wr[k];
    h[g] = acc;
}

// res = h (+ res_prev); hn = LN(res)*w+b -> bf16 hi/lo
__global__ void k_resln(const float* __restrict__ h, float* __restrict__ res,
                        unsigned short* __restrict__ hnhi, unsigned short* __restrict__ hnlo,
                        const float* __restrict__ w, const float* __restrict__ b, int addRes){
    int wv = threadIdx.x >> 6, lane = threadIdx.x & 63;
    int bt = blockIdx.x*4 + wv;
    float4 v = ((const float4*)(h + (size_t)bt*DM))[lane];
    if(addRes){
        float4 r = ((const float4*)(res + (size_t)bt*DM))[lane];
        v.x+=r.x; v.y+=r.y; v.z+=r.z; v.w+=r.w;
    }
    ((float4*)(res + (size_t)bt*DM))[lane] = v;
    float s  = v.x+v.y+v.z+v.w;
    float ss = v.x*v.x+v.y*v.y+v.z*v.z+v.w*v.w;
#pragma unroll
    for(int m=1;m<64;m<<=1){ s += __shfl_xor(s,m); ss += __shfl_xor(ss,m); }
    float mean = s*(1.f/DM);
    float var  = ss*(1.f/DM) - mean*mean;
    float inv  = rsqrtf(var + 1e-5f);
    float4 wt = ((const float4*)w)[lane];
    float4 bs = ((const float4*)b)[lane];
    float4 o;
    o.x = (v.x-mean)*inv*wt.x + bs.x;
    o.y = (v.y-mean)*inv*wt.y + bs.y;
    o.z = (v.z-mean)*inv*wt.z + bs.z;
    o.w = (v.w-mean)*inv*wt.w + bs.w;
    ushort4 hh, ll;
    hh.x = f2bf(o.x); ll.x = f2bf(o.x - bf2f(hh.x));
    hh.y = f2bf(o.y); ll.y = f2bf(o.y - bf2f(hh.y));
    hh.z = f2bf(o.z); ll.z = f2bf(o.z - bf2f(hh.z));
    hh.w = f2bf(o.w); ll.w = f2bf(o.w - bf2f(hh.w));
    ((ushort4*)(hnhi + (size_t)bt*DM))[lane] = hh;
    ((ushort4*)(hnlo + (size_t)bt*DM))[lane] = ll;
}

// C[M][N] = A[M][K] @ Bw[N][K]^T via bf16 MFMA, hi/lo 3-term split (inproj)
template<int BM,int BN>
__global__ void __launch_bounds__(256) k_gemm_bf3(
    const unsigned short* __restrict__ Ahi, const unsigned short* __restrict__ Alo,
    const unsigned short* __restrict__ Bhi, const unsigned short* __restrict__ Blo,
    float* __restrict__ C, int M, int N, int K)
{
    constexpr int LDP = 40;
    constexpr int WM = BM/2, WN = BN/2;
    constexpr int MI_ = WM/16, NI_ = WN/16;
    __shared__ unsigned short sAh[BM*LDP], sAl[BM*LDP], sBh[BN*LDP], sBl[BN*LDP];
    int tid  = threadIdx.x;
    int wave = tid >> 6, lane = tid & 63;
    int wm0  = (wave >> 1) * WM, wn0 = (wave & 1) * WN;
    int m0   = blockIdx.y * BM, n0 = blockIdx.x * BN;
    int lr   = lane & 15;
    int kq   = (lane >> 4) * 8;
    int quad4 = (lane >> 4) * 4;

    f32x4 acc[MI_][NI_];
#pragma unroll
    for(int i=0;i<MI_;i++)
#pragma unroll
        for(int j=0;j<NI_;j++) acc[i][j] = (f32x4){0.f,0.f,0.f,0.f};

    for(int k0=0;k0<K;k0+=32){
#pragma unroll
        for(int i=tid;i<BM*4;i+=256){
            int r = i>>2, cg = (i&3)*8;
            size_t go = (size_t)(m0+r)*K + k0 + cg;
            *(float4*)(&sAh[r*LDP + cg]) = *(const float4*)(Ahi + go);
            *(float4*)(&sAl[r*LDP + cg]) = *(const float4*)(Alo + go);
        }
#pragma unroll
        for(int i=tid;i<BN*4;i+=256){
            int r = i>>2, cg = (i&3)*8;
            size_t go = (size_t)(n0+r)*K + k0 + cg;
            *(float4*)(&sBh[r*LDP + cg]) = *(const float4*)(Bhi + go);
            *(float4*)(&sBl[r*LDP + cg]) = *(const float4*)(Blo + go);
        }
        __syncthreads();
        bf16x8 ah[MI_], al[MI_], bh[NI_], bl[NI_];
#pragma unroll
        for(int mi=0;mi<MI_;mi++){
            int ro = (wm0 + mi*16 + lr)*LDP + kq;
            ah[mi] = *(const bf16x8*)(&sAh[ro]);
            al[mi] = *(const bf16x8*)(&sAl[ro]);
        }
#pragma unroll
        for(int ni=0;ni<NI_;ni++){
            int ro = (wn0 + ni*16 + lr)*LDP + kq;
            bh[ni] = *(const bf16x8*)(&sBh[ro]);
            bl[ni] = *(const bf16x8*)(&sBl[ro]);
        }
#pragma unroll
        for(int mi=0;mi<MI_;mi++)
#pragma unroll
            for(int ni=0;ni<NI_;ni++){
                acc[mi][ni] = __builtin_amdgcn_mfma_f32_16x16x32_bf16(ah[mi], bh[ni], acc[mi][ni], 0,0,0);
                acc[mi][ni] = __builtin_amdgcn_mfma_f32_16x16x32_bf16(ah[mi], bl[ni], acc[mi][ni], 0,0,0);
                acc[mi][ni] = __builtin_amdgcn_mfma_f32_16x16x32_bf16(al[mi], bh[ni], acc[mi][ni], 0,0,0);
            }
        __syncthreads();
    }
#pragma unroll
    for(int mi=0;mi<MI_;mi++)
#pragma unroll
        for(int ni=0;ni<NI_;ni++){
            int col = n0 + wn0 + ni*16 + lr;
#pragma unroll
            for(int r=0;r<4;r++){
                int row = m0 + wm0 + mi*16 + quad4 + r;
                C[(size_t)row*N + col] = acc[mi][ni][r];
            }
        }
}

// ---- outproj: same GEMM but A rows are packed (hi | lo<<16) uints from scan3 ----
template<int BM,int BN>
__global__ void __launch_bounds__(256) k_gemm_pk(
    const unsigned* __restrict__ Apk,
    const unsigned short* __restrict__ Bhi, const unsigned short* __restrict__ Blo,
    float* __restrict__ C, int M, int N, int K)
{
    constexpr int LDP = 40;
    constexpr int WM = BM/2, WN = BN/2;
    constexpr int MI_ = WM/16, NI_ = WN/16;
    __shared__ unsigned short sAh[BM*LDP], sAl[BM*LDP], sBh[BN*LDP], sBl[BN*LDP];
    int tid  = threadIdx.x;
    int wave = tid >> 6, lane = tid & 63;
    int wm0  = (wave >> 1) * WM, wn0 = (wave & 1) * WN;
    int m0   = blockIdx.y * BM, n0 = blockIdx.x * BN;
    int lr   = lane & 15;
    int kq   = (lane >> 4) * 8;
    int quad4 = (lane >> 4) * 4;

    f32x4 acc[MI_][NI_];
#pragma unroll
    for(int i=0;i<MI_;i++)
#pragma unroll
        for(int j=0;j<NI_;j++) acc[i][j] = (f32x4){0.f,0.f,0.f,0.f};

    for(int k0=0;k0<K;k0+=32){
#pragma unroll
        for(int i=tid;i<BM*2;i+=256){
            int r = i>>1, hf = (i&1)*16;
            const uint4* yp = (const uint4*)(Apk + (size_t)(m0+r)*K + k0 + hf);
#pragma unroll
            for(int q=0;q<4;q++){
                uint4 p = yp[q];
                ushort4 H, L;
                H.x=(unsigned short)p.x;  L.x=(unsigned short)(p.x>>16);
                H.y=(unsigned short)p.y;  L.y=(unsigned short)(p.y>>16);
                H.z=(unsigned short)p.z;  L.z=(unsigned short)(p.z>>16);
                H.w=(unsigned short)p.w;  L.w=(unsigned short)(p.w>>16);
                *(ushort4*)(&sAh[r*LDP + hf + q*4]) = H;
                *(ushort4*)(&sAl[r*LDP + hf + q*4]) = L;
            }
        }
#pragma unroll
        for(int i=tid;i<BN*4;i+=256){
            int r = i>>2, cg = (i&3)*8;
            size_t go = (size_t)(n0+r)*K + k0 + cg;
            *(float4*)(&sBh[r*LDP + cg]) = *(const float4*)(Bhi + go);
            *(float4*)(&sBl[r*LDP + cg]) = *(const float4*)(Blo + go);
        }
        __syncthreads();
        bf16x8 ah[MI_], al[MI_], bh[NI_], bl[NI_];
#pragma unroll
        for(int mi=0;mi<MI_;mi++){
            int ro = (wm0 + mi*16 + lr)*LDP + kq;
            ah[mi] = *(const bf16x8*)(&sAh[ro]);
            al[mi] = *(const bf16x8*)(&sAl[ro]);
        }
#pragma unroll
        for(int ni=0;ni<NI_;ni++){
            int ro = (wn0 + ni*16 + lr)*LDP + kq;
            bh[ni] = *(const bf16x8*)(&sBh[ro]);
            bl[ni] = *(const bf16x8*)(&sBl[ro]);
        }
#pragma unroll
        for(int mi=0;mi<MI_;mi++)
#pragma unroll
            for(int ni=0;ni<NI_;ni++){
                acc[mi][ni] = __builtin_amdgcn_mfma_f32_16x16x32_bf16(ah[mi], bh[ni], acc[mi][ni], 0,0,0);
                acc[mi][ni] = __builtin_amdgcn_mfma_f32_16x16x32_bf16(ah[mi], bl[ni], acc[mi][ni], 0,0,0);
                acc[mi][ni] = __builtin_amdgcn_mfma_f32_16x16x32_bf16(al[mi], bh[ni], acc[mi][ni], 0,0,0);
            }
        __syncthreads();
    }
#pragma unroll
    for(int mi=0;mi<MI_;mi++)
#pragma unroll
        for(int ni=0;ni<NI_;ni++){
            int col = n0 + wn0 + ni*16 + lr;
#pragma unroll
            for(int r=0;r<4;r++){
                int row = m0 + wm0 + mi*16 + quad4 + r;
                C[(size_t)row*N + col] = acc[mi][ni][r];
            }
        }
}

// ---- conv + SiLU, elementwise, float4 over 4 d-channels; writes xh fp32 + packed bf16 ----
__global__ void k_conv4(const float* __restrict__ xz, const float* __restrict__ cw,
                        const float* __restrict__ cb, float* __restrict__ xh,
                        unsigned* __restrict__ xhp){
    int g  = blockIdx.x*256 + threadIdx.x;   // (bt, d/4)
    int bt = g >> 7, dq = g & 127;
    int d  = dq << 2;
    int t  = bt & (T_-1);
    float4 z4 = make_float4(0.f,0.f,0.f,0.f);
    float4 x3 = *(const float4*)(xz + (size_t)bt*DX + d);
    float4 x2 = (t>=1) ? *(const float4*)(xz + (size_t)(bt-1)*DX + d) : z4;
    float4 x1 = (t>=2) ? *(const float4*)(xz + (size_t)(bt-2)*DX + d) : z4;
    float4 x0 = (t>=3) ? *(const float4*)(xz + (size_t)(bt-3)*DX + d) : z4;
    float4 b4 = *(const float4*)(cb + d);
    float4 w0 = *(const float4*)(cw + (size_t)(d+0)*4);
    float4 w1 = *(const float4*)(cw + (size_t)(d+1)*4);
    float4 w2 = *(const float4*)(cw + (size_t)(d+2)*4);
    float4 w3 = *(const float4*)(cw + (size_t)(d+3)*4);
    float4 o;
    o.x = b4.x + w0.x*x0.x + w0.y*x1.x + w0.z*x2.x + w0.w*x3.x;
    o.y = b4.y + w1.x*x0.y + w1.y*x1.y + w1.z*x2.y + w1.w*x3.y;
    o.z = b4.z + w2.x*x0.z + w2.y*x1.z + w2.z*x2.z + w2.w*x3.z;
    o.w = b4.w + w3.x*x0.w + w3.y*x1.w + w3.z*x2.w + w3.w*x3.w;
    o.x = o.x * sigmoidf_(o.x);
    o.y = o.y * sigmoidf_(o.y);
    o.z = o.z * sigmoidf_(o.z);
    o.w = o.w * sigmoidf_(o.w);
    *(float4*)(xh + (size_t)bt*DI + d) = o;
    uint4 pk;
    pk.x = packbf(o.x); pk.y = packbf(o.y); pk.z = packbf(o.z); pk.w = packbf(o.w);
    *(uint4*)(xhp + (size_t)bt*DI + d) = pk;
}

// ---- xproj MFMA + dtproj (A staged from packed xh) ----
__global__ void __launch_bounds__(512) k_xpdt(
    const unsigned* __restrict__ xhp,
    const unsigned short* __restrict__ Bhi, const unsigned short* __restrict__ Blo,
    const float* __restrict__ dtW, const float* __restrict__ dtbias,
    float* __restrict__ bc, float* __restrict__ dtO)
{
    __shared__ unsigned short sAh[16*520], sAl[16*520];
    __shared__ float dls[16*17];

    int tid = threadIdx.x;
    int wave = tid >> 6, lane = tid & 63;
    int lr = lane & 15, kq = (lane>>4)*8, quad4 = (lane>>4)*4;
    int m0 = blockIdx.x * LCH;
    int d  = tid;

    // stage A: 16 rows x 512 cols from packed
#pragma unroll
    for(int i=0;i<4;i++){
        int e = tid + i*512;           // uint4 index, 2048 total
        int r = e >> 7, cg = (e & 127) * 4;
        uint4 p = *(const uint4*)(xhp + (size_t)(m0+r)*DI + cg);
        ushort4 H, L;
        H.x=(unsigned short)p.x; L.x=(unsigned short)(p.x>>16);
        H.y=(unsigned short)p.y; L.y=(unsigned short)(p.y>>16);
        H.z=(unsigned short)p.z; L.z=(unsigned short)(p.z>>16);
        H.w=(unsigned short)p.w; L.w=(unsigned short)(p.w>>16);
        *(ushort4*)(&sAh[r*520 + cg]) = H;
        *(ushort4*)(&sAl[r*520 + cg]) = L;
    }
    float wr_[16]; ld16(dtW + (size_t)d*16, wr_);
    float bsv = dtbias[d];
    __syncthreads();

    // xproj MFMA, waves 0-2 = n-tiles, B streamed from L2
    f32x4 acc = {0.f,0.f,0.f,0.f};
    if(wave < 3){
#pragma unroll 4
        for(int ks=0;ks<16;ks++){
            int ao = lr*520 + ks*32 + kq;
            bf16x8 ah = *(const bf16x8*)(&sAh[ao]);
            bf16x8 al = *(const bf16x8*)(&sAl[ao]);
            size_t wo = (size_t)(wave*16 + lr)*DI + ks*32 + kq;
            bf16x8 bh = *(const bf16x8*)(Bhi + wo);
            bf16x8 bl = *(const bf16x8*)(Blo + wo);
            acc = __builtin_amdgcn_mfma_f32_16x16x32_bf16(ah, bh, acc, 0,0,0);
            acc = __builtin_amdgcn_mfma_f32_16x16x32_bf16(ah, bl, acc, 0,0,0);
            acc = __builtin_amdgcn_mfma_f32_16x16x32_bf16(al, bh, acc, 0,0,0);
        }
        if(wave == 0){
#pragma unroll
            for(int r=0;r<4;r++) dls[(quad4+r)*17 + lr] = acc[r];
        } else if(wave == 1){
#pragma unroll
            for(int r=0;r<4;r++) bc[(size_t)(m0+quad4+r)*32 + lr] = acc[r];
        } else {
#pragma unroll
            for(int r=0;r<4;r++) bc[(size_t)(m0+quad4+r)*32 + 16 + lr] = acc[r];
        }
    }
    __syncthreads();

    // dtproj + softplus
#pragma unroll
    for(int t=0;t<16;t++){
        float acc2 = bsv;
#pragma unroll
        for(int r=0;r<16;r++) acc2 += dls[t*17 + r]*wr_[r];
        float sp = fmaxf(acc2,0.f) + log1pf(__expf(-fabsf(acc2)));
        dtO[(size_t)(m0+t)*DI + d] = sp;
    }
}

// ---- scan pass-1 ----
__global__ void __launch_bounds__(256) k_scan1(const float* __restrict__ dt,
    const float* __restrict__ xh, const float* __restrict__ bc,
    const float* __restrict__ A_log, float* __restrict__ S, float* __restrict__ sdt){
    int d = blockIdx.x*256 + threadIdx.x;
    int c = blockIdx.y, b = blockIdx.z;
    float a_[16]; ld16(A_log + (size_t)d*16, a_);
#pragma unroll
    for(int n=0;n<16;n++) a_[n] = -__expf(a_[n]);
    float st_[16];
#pragma unroll
    for(int n=0;n<16;n++) st_[n] = 0.f;
    float sd = 0.f;
    int base = b*T_ + c*LCH;
#pragma unroll 4
    for(int t=0;t<LCH;t++){
        int bt = base + t;
        float dtv = dt[(size_t)bt*DI + d];
        float xhv = xh[(size_t)bt*DI + d];
        float bv[16]; ld16(bc + (size_t)bt*32, bv);
        float dx = dtv*xhv;
        sd += dtv;
#pragma unroll
        for(int n=0;n<16;n++) st_[n] = __expf(dtv*a_[n])*st_[n] + dx*bv[n];
    }
    st16(S + (((size_t)b*NC_ + c)*DI + d)*16, st_);
    sdt[((size_t)b*NC_ + c)*DI + d] = sd;
}

// ---- pass 2: inter-chunk scan ----
__global__ void k_scan2(const float* __restrict__ S, const float* __restrict__ sdt,
                        const float* __restrict__ A_log, float* __restrict__ Hinit){
    int g = blockIdx.x*256 + threadIdx.x;
    int b = g >> 13;
    int dn = g & 8191;
    int d = dn >> 4;
    float a = -__expf(A_log[dn]);
    float H = 0.f;
    for(int c=0;c<NC_;c++){
        size_t o = ((size_t)(b*NC_ + c))*8192 + dn;
        Hinit[o] = H;
        float sd = sdt[(size_t)(b*NC_ + c)*DI + d];
        H = __expf(sd*a)*H + S[o];
    }
}

// ---- scan pass-3: replay + gate, packed Y out ----
__global__ void __launch_bounds__(256) k_scan3(
    const float* __restrict__ dt, const float* __restrict__ xh, const float* __restrict__ xz,
    const float* __restrict__ bc, const float* __restrict__ A_log, const float* __restrict__ Dpar,
    const float* __restrict__ Hinit, unsigned* __restrict__ Y)
{
    __shared__ float sbc[16*36];
    int tid = threadIdx.x;
    int c = blockIdx.y, b = blockIdx.z;
    int m0 = b*T_ + c*LCH;
    if(tid < 128){
        int t = tid >> 3, s = tid & 7;
        *(float4*)(&sbc[t*36 + s*4]) = *(const float4*)(bc + (size_t)(m0+t)*32 + s*4);
    }
    __syncthreads();
    int d = blockIdx.x*256 + tid;
    float a_[16]; ld16(A_log + (size_t)d*16, a_);
#pragma unroll
    for(int n=0;n<16;n++) a_[n] = -__expf(a_[n]);
    float st_[16]; ld16(Hinit + (((size_t)b*NC_ + c)*DI + d)*16, st_);
    float Dp = Dpar[d];
#pragma unroll 4
    for(int t=0;t<LCH;t++){
        int bt = m0 + t;
        float dtv = dt[(size_t)bt*DI + d];
        float xhv = xh[(size_t)bt*DI + d];
        float bv[16]; ld16(&sbc[t*36], bv);
        float cv[16]; ld16(&sbc[t*36 + 16], cv);
        float dx = dtv*xhv;
        float y = 0.f;
#pragma unroll
        for(int n=0;n<16;n++){
            st_[n] = __expf(dtv*a_[n])*st_[n] + dx*bv[n];
            y += st_[n]*cv[n];
        }
        float zv = xz[(size_t)bt*DX + DI + d];
        y += Dp*xhv;
        y = y * zv * sigmoidf_(zv);
        unsigned short hh = f2bf(y);
        unsigned short ll = f2bf(y - bf2f(hh));
        Y[(size_t)bt*DI + d] = (unsigned)hh | ((unsigned)ll << 16);
    }
}

// out[bt] = dot(h[bt, :256], out_W)
__global__ void k_outw(const float* __restrict__ h, const float* __restrict__ ow,
                       float* __restrict__ out){
    int wv = threadIdx.x >> 6, lane = threadIdx.x & 63;
    int bt = blockIdx.x*4 + wv;
    float4 v = ((const float4*)(h + (size_t)bt*DM))[lane];
    float4 w = ((const float4*)ow)[lane];
    float s = v.x*w.x + v.y*w.y + v.z*w.z + v.w*w.w;
#pragma unroll
    for(int m=1;m<64;m<<=1) s += __shfl_xor(s,m);
    if(lane==0) out[bt] = s;
}

extern "C" void kernel_launch(void* const* d_in, const int* in_sizes, int n_in,
                              void* d_out, int out_size, void* d_ws, size_t ws_size,
                              hipStream_t stream){
    const float* x_src    = (const float*)d_in[0];
    const float* in_W     = (const float*)d_in[2];
    const float* norm_w   = (const float*)d_in[3];
    const float* norm_b   = (const float*)d_in[4];
    const float* inproj_W = (const float*)d_in[5];
    const float* conv_w   = (const float*)d_in[6];
    const float* conv_b   = (const float*)d_in[7];
    const float* xproj_W  = (const float*)d_in[8];
    const float* dtproj_W = (const float*)d_in[9];
    const float* dtproj_b = (const float*)d_in[10];
    const float* A_log    = (const float*)d_in[11];
    const float* D_param  = (const float*)d_in[12];
    const float* outproj_W= (const float*)d_in[13];
    const float* out_W    = (const float*)d_in[14];

    float* ws  = (float*)d_ws;
    float* h    = ws;                        // BT*DM
    float* res  = h    + (size_t)BT_*DM;     // BT*DM
    float* xz   = res  + (size_t)BT_*DM;     // BT*DX
    float* xh   = xz   + (size_t)BT_*DX;     // BT*DI
    float* bcb  = xh   + (size_t)BT_*DI;     // BT*32
    float* dtb  = bcb  + (size_t)BT_*32;     // BT*DI
    float* sdtb = dtb  + (size_t)BT_*DI;     // B*NC*DI
    float* Sbuf = sdtb + (size_t)B_*NC_*DI;  // B*NC*DI*16
    float* Hbuf = Sbuf + (size_t)B_*NC_*DI*DS_;
    unsigned short* us = (unsigned short*)(Hbuf + (size_t)B_*NC_*DI*DS_);
    unsigned short* WhiIn  = us;                                  // NL*DX*DM
    unsigned short* WloIn  = WhiIn  + (size_t)NL*DX*DM;
    unsigned short* WhiOut = WloIn  + (size_t)NL*DX*DM;           // NL*DM*DI
    unsigned short* WloOut = WhiOut + (size_t)NL*DM*DI;
    unsigned short* WhiXp  = WloOut + (size_t)NL*DM*DI;           // NL*NO*DI
    unsigned short* WloXp  = WhiXp  + (size_t)NL*NO_*DI;
    unsigned short* hnhi   = WloXp  + (size_t)NL*NO_*DI;          // BT*DM
    unsigned short* hnlo   = hnhi   + (size_t)BT_*DM;
    unsigned*       ybuf   = (unsigned*)(hnlo + (size_t)BT_*DM);  // BT*DI
    unsigned*       xhp    = ybuf + (size_t)BT_*DI;               // BT*DI

    k_cvtW<<<(NL*DX*DM/4 + 255)/256, 256, 0, stream>>>(inproj_W,  WhiIn,  WloIn,  NL*DX*DM/4);
    k_cvtW<<<(NL*DM*DI/4 + 255)/256, 256, 0, stream>>>(outproj_W, WhiOut, WloOut, NL*DM*DI/4);
    k_cvtW<<<(NL*NO_*DI/4 + 255)/256, 256, 0, stream>>>(xproj_W, WhiXp, WloXp, NL*NO_*DI/4);
    k_ingemm<<<BT_*DM/256, 256, 0, stream>>>(x_src, in_W, h);
    for(int i=0;i<NL;i++){
        k_resln<<<BT_/4, 256, 0, stream>>>(h, res, hnhi, hnlo, norm_w + i*DM, norm_b + i*DM, i>0 ? 1 : 0);
        k_gemm_bf3<128,128><<<dim3(DX/128, BT_/128), 256, 0, stream>>>(
            hnhi, hnlo, WhiIn + (size_t)i*DX*DM, WloIn + (size_t)i*DX*DM, xz, BT_, DX, DM);
        k_conv4<<<BT_*DI/4/256, 256, 0, stream>>>(xz, conv_w + i*DI*4, conv_b + i*DI, xh, xhp);
        k_xpdt<<<BT_/LCH, 512, 0, stream>>>(xhp,
            WhiXp + (size_t)i*NO_*DI, WloXp + (size_t)i*NO_*DI,
            dtproj_W + (size_t)i*DI*DR_, dtproj_b + i*DI, bcb, dtb);
        k_scan1<<<dim3(2, NC_, B_), 256, 0, stream>>>(dtb, xh, bcb,
            A_log + (size_t)i*DI*DS_, Sbuf, sdtb);
        k_scan2<<<B_*DI*DS_/256, 256, 0, stream>>>(Sbuf, sdtb, A_log + (size_t)i*DI*DS_, Hbuf);
        k_scan3<<<dim3(2, NC_, B_), 256, 0, stream>>>(dtb, xh, xz, bcb, A_log + (size_t)i*DI*DS_,
            D_param + i*DI, Hbuf, ybuf);
        k_gemm_pk<128,64><<<dim3(DM/64, BT_/128), 256, 0, stream>>>(
            ybuf, WhiOut + (size_t)i*DM*DI, WloOut + (size_t)i*DM*DI, h, BT_, DM, DI);
    }
    k_outw<<<BT_/4, 256, 0, stream>>>(h, out_W, (float*)d_out);
}

// Round 12
// 625.827 us; speedup vs baseline: 1.1047x; 1.1047x over previous
//
#include <hip/hip_runtime.h>

#define B_   4
#define T_   2048
#define BT_  8192
#define INL  15
#define DM   256
#define DI   512
#define DX   1024
#define DS_  16
#define DR_  16
#define NO_  48
#define NL   4
#define NC_  128
#define LCH  16

typedef short bf16x8 __attribute__((ext_vector_type(8)));
typedef float f32x4  __attribute__((ext_vector_type(4)));

__device__ __forceinline__ float sigmoidf_(float x){ return 1.f/(1.f+__expf(-x)); }

__device__ __forceinline__ unsigned short f2bf(float x){
    union { float f; unsigned u; } v; v.f = x;
    unsigned r = (v.u + 0x7FFFu + ((v.u >> 16) & 1u)) >> 16;
    return (unsigned short)r;
}
__device__ __forceinline__ float bf2f(unsigned short h){
    union { unsigned u; float f; } v; v.u = ((unsigned)h) << 16;
    return v.f;
}

__device__ __forceinline__ void ld16(const float* __restrict__ p, float* v){
    const float4* q = (const float4*)p;
    float4 x0=q[0],x1=q[1],x2=q[2],x3=q[3];
    v[0]=x0.x; v[1]=x0.y; v[2]=x0.z; v[3]=x0.w;
    v[4]=x1.x; v[5]=x1.y; v[6]=x1.z; v[7]=x1.w;
    v[8]=x2.x; v[9]=x2.y; v[10]=x2.z; v[11]=x2.w;
    v[12]=x3.x; v[13]=x3.y; v[14]=x3.z; v[15]=x3.w;
}
__device__ __forceinline__ void st16(float* __restrict__ p, const float* v){
    float4* q = (float4*)p;
    q[0] = make_float4(v[0],v[1],v[2],v[3]);
    q[1] = make_float4(v[4],v[5],v[6],v[7]);
    q[2] = make_float4(v[8],v[9],v[10],v[11]);
    q[3] = make_float4(v[12],v[13],v[14],v[15]);
}

// convert fp32 array -> bf16 hi/lo split
__global__ void k_cvtW(const float* __restrict__ W, unsigned short* __restrict__ hi,
                       unsigned short* __restrict__ lo, int n4){
    int g = blockIdx.x*256 + threadIdx.x;
    if(g >= n4) return;
    float4 v = ((const float4*)W)[g];
    ushort4 h, l;
    h.x = f2bf(v.x); l.x = f2bf(v.x - bf2f(h.x));
    h.y = f2bf(v.y); l.y = f2bf(v.y - bf2f(h.y));
    h.z = f2bf(v.z); l.z = f2bf(v.z - bf2f(h.z));
    h.w = f2bf(v.w); l.w = f2bf(v.w - bf2f(h.w));
    ((ushort4*)hi)[g] = h;
    ((ushort4*)lo)[g] = l;
}

// h[bt][m] = sum_k x[bt][k] * in_W[m][k]
__global__ void k_ingemm(const float* __restrict__ x, const float* __restrict__ W,
                         float* __restrict__ h){
    int g  = blockIdx.x*256 + threadIdx.x;
    int bt = g >> 8, m = g & 255;
    const float* xr = x + bt*INL;
    const float* wr = W + m*INL;
    float acc = 0.f;
#pragma unroll
    for(int k=0;k<INL;k++) acc += xr[k]*wr[k];
    h[g] = acc;
}

// res = h (+ res_prev); hn = LN(res)*w+b -> bf16 hi/lo
__global__ void k_resln(const float* __restrict__ h, float* __restrict__ res,
                        unsigned short* __restrict__ hnhi, unsigned short* __restrict__ hnlo,
                        const float* __restrict__ w, const float* __restrict__ b, int addRes){
    int wv = threadIdx.x >> 6, lane = threadIdx.x & 63;
    int bt = blockIdx.x*4 + wv;
    float4 v = ((const float4*)(h + (size_t)bt*DM))[lane];
    if(addRes){
        float4 r = ((const float4*)(res + (size_t)bt*DM))[lane];
        v.x+=r.x; v.y+=r.y; v.z+=r.z; v.w+=r.w;
    }
    ((float4*)(res + (size_t)bt*DM))[lane] = v;
    float s  = v.x+v.y+v.z+v.w;
    float ss = v.x*v.x+v.y*v.y+v.z*v.z+v.w*v.w;
#pragma unroll
    for(int m=1;m<64;m<<=1){ s += __shfl_xor(s,m); ss += __shfl_xor(ss,m); }
    float mean = s*(1.f/DM);
    float var  = ss*(1.f/DM) - mean*mean;
    float inv  = rsqrtf(var + 1e-5f);
    float4 wt = ((const float4*)w)[lane];
    float4 bs = ((const float4*)b)[lane];
    float4 o;
    o.x = (v.x-mean)*inv*wt.x + bs.x;
    o.y = (v.y-mean)*inv*wt.y + bs.y;
    o.z = (v.z-mean)*inv*wt.z + bs.z;
    o.w = (v.w-mean)*inv*wt.w + bs.w;
    ushort4 hh, ll;
    hh.x = f2bf(o.x); ll.x = f2bf(o.x - bf2f(hh.x));
    hh.y = f2bf(o.y); ll.y = f2bf(o.y - bf2f(hh.y));
    hh.z = f2bf(o.z); ll.z = f2bf(o.z - bf2f(hh.z));
    hh.w = f2bf(o.w); ll.w = f2bf(o.w - bf2f(hh.w));
    ((ushort4*)(hnhi + (size_t)bt*DM))[lane] = hh;
    ((ushort4*)(hnlo + (size_t)bt*DM))[lane] = ll;
}

// C[M][N] = A[M][K] @ Bw[N][K]^T via bf16 MFMA, hi/lo 3-term split (inproj)
template<int BM,int BN>
__global__ void __launch_bounds__(256) k_gemm_bf3(
    const unsigned short* __restrict__ Ahi, const unsigned short* __restrict__ Alo,
    const unsigned short* __restrict__ Bhi, const unsigned short* __restrict__ Blo,
    float* __restrict__ C, int M, int N, int K)
{
    constexpr int LDP = 40;
    constexpr int WM = BM/2, WN = BN/2;
    constexpr int MI_ = WM/16, NI_ = WN/16;
    __shared__ unsigned short sAh[BM*LDP], sAl[BM*LDP], sBh[BN*LDP], sBl[BN*LDP];
    int tid  = threadIdx.x;
    int wave = tid >> 6, lane = tid & 63;
    int wm0  = (wave >> 1) * WM, wn0 = (wave & 1) * WN;
    int m0   = blockIdx.y * BM, n0 = blockIdx.x * BN;
    int lr   = lane & 15;
    int kq   = (lane >> 4) * 8;
    int quad4 = (lane >> 4) * 4;

    f32x4 acc[MI_][NI_];
#pragma unroll
    for(int i=0;i<MI_;i++)
#pragma unroll
        for(int j=0;j<NI_;j++) acc[i][j] = (f32x4){0.f,0.f,0.f,0.f};

    for(int k0=0;k0<K;k0+=32){
#pragma unroll
        for(int i=tid;i<BM*4;i+=256){
            int r = i>>2, cg = (i&3)*8;
            size_t go = (size_t)(m0+r)*K + k0 + cg;
            *(float4*)(&sAh[r*LDP + cg]) = *(const float4*)(Ahi + go);
            *(float4*)(&sAl[r*LDP + cg]) = *(const float4*)(Alo + go);
        }
#pragma unroll
        for(int i=tid;i<BN*4;i+=256){
            int r = i>>2, cg = (i&3)*8;
            size_t go = (size_t)(n0+r)*K + k0 + cg;
            *(float4*)(&sBh[r*LDP + cg]) = *(const float4*)(Bhi + go);
            *(float4*)(&sBl[r*LDP + cg]) = *(const float4*)(Blo + go);
        }
        __syncthreads();
        bf16x8 ah[MI_], al[MI_], bh[NI_], bl[NI_];
#pragma unroll
        for(int mi=0;mi<MI_;mi++){
            int ro = (wm0 + mi*16 + lr)*LDP + kq;
            ah[mi] = *(const bf16x8*)(&sAh[ro]);
            al[mi] = *(const bf16x8*)(&sAl[ro]);
        }
#pragma unroll
        for(int ni=0;ni<NI_;ni++){
            int ro = (wn0 + ni*16 + lr)*LDP + kq;
            bh[ni] = *(const bf16x8*)(&sBh[ro]);
            bl[ni] = *(const bf16x8*)(&sBl[ro]);
        }
#pragma unroll
        for(int mi=0;mi<MI_;mi++)
#pragma unroll
            for(int ni=0;ni<NI_;ni++){
                acc[mi][ni] = __builtin_amdgcn_mfma_f32_16x16x32_bf16(ah[mi], bh[ni], acc[mi][ni], 0,0,0);
                acc[mi][ni] = __builtin_amdgcn_mfma_f32_16x16x32_bf16(ah[mi], bl[ni], acc[mi][ni], 0,0,0);
                acc[mi][ni] = __builtin_amdgcn_mfma_f32_16x16x32_bf16(al[mi], bh[ni], acc[mi][ni], 0,0,0);
            }
        __syncthreads();
    }
#pragma unroll
    for(int mi=0;mi<MI_;mi++)
#pragma unroll
        for(int ni=0;ni<NI_;ni++){
            int col = n0 + wn0 + ni*16 + lr;
#pragma unroll
            for(int r=0;r<4;r++){
                int row = m0 + wm0 + mi*16 + quad4 + r;
                C[(size_t)row*N + col] = acc[mi][ni][r];
            }
        }
}

// ---- outproj: same GEMM but A rows are packed (hi | lo<<16) uints from scan3 ----
template<int BM,int BN>
__global__ void __launch_bounds__(256) k_gemm_pk(
    const unsigned* __restrict__ Apk,
    const unsigned short* __restrict__ Bhi, const unsigned short* __restrict__ Blo,
    float* __restrict__ C, int M, int N, int K)
{
    constexpr int LDP = 40;
    constexpr int WM = BM/2, WN = BN/2;
    constexpr int MI_ = WM/16, NI_ = WN/16;
    __shared__ unsigned short sAh[BM*LDP], sAl[BM*LDP], sBh[BN*LDP], sBl[BN*LDP];
    int tid  = threadIdx.x;
    int wave = tid >> 6, lane = tid & 63;
    int wm0  = (wave >> 1) * WM, wn0 = (wave & 1) * WN;
    int m0   = blockIdx.y * BM, n0 = blockIdx.x * BN;
    int lr   = lane & 15;
    int kq   = (lane >> 4) * 8;
    int quad4 = (lane >> 4) * 4;

    f32x4 acc[MI_][NI_];
#pragma unroll
    for(int i=0;i<MI_;i++)
#pragma unroll
        for(int j=0;j<NI_;j++) acc[i][j] = (f32x4){0.f,0.f,0.f,0.f};

    for(int k0=0;k0<K;k0+=32){
#pragma unroll
        for(int i=tid;i<BM*2;i+=256){
            int r = i>>1, hf = (i&1)*16;
            const uint4* yp = (const uint4*)(Apk + (size_t)(m0+r)*K + k0 + hf);
#pragma unroll
            for(int q=0;q<4;q++){
                uint4 p = yp[q];
                ushort4 H, L;
                H.x=(unsigned short)p.x;  L.x=(unsigned short)(p.x>>16);
                H.y=(unsigned short)p.y;  L.y=(unsigned short)(p.y>>16);
                H.z=(unsigned short)p.z;  L.z=(unsigned short)(p.z>>16);
                H.w=(unsigned short)p.w;  L.w=(unsigned short)(p.w>>16);
                *(ushort4*)(&sAh[r*LDP + hf + q*4]) = H;
                *(ushort4*)(&sAl[r*LDP + hf + q*4]) = L;
            }
        }
#pragma unroll
        for(int i=tid;i<BN*4;i+=256){
            int r = i>>2, cg = (i&3)*8;
            size_t go = (size_t)(n0+r)*K + k0 + cg;
            *(float4*)(&sBh[r*LDP + cg]) = *(const float4*)(Bhi + go);
            *(float4*)(&sBl[r*LDP + cg]) = *(const float4*)(Blo + go);
        }
        __syncthreads();
        bf16x8 ah[MI_], al[MI_], bh[NI_], bl[NI_];
#pragma unroll
        for(int mi=0;mi<MI_;mi++){
            int ro = (wm0 + mi*16 + lr)*LDP + kq;
            ah[mi] = *(const bf16x8*)(&sAh[ro]);
            al[mi] = *(const bf16x8*)(&sAl[ro]);
        }
#pragma unroll
        for(int ni=0;ni<NI_;ni++){
            int ro = (wn0 + ni*16 + lr)*LDP + kq;
            bh[ni] = *(const bf16x8*)(&sBh[ro]);
            bl[ni] = *(const bf16x8*)(&sBl[ro]);
        }
#pragma unroll
        for(int mi=0;mi<MI_;mi++)
#pragma unroll
            for(int ni=0;ni<NI_;ni++){
                acc[mi][ni] = __builtin_amdgcn_mfma_f32_16x16x32_bf16(ah[mi], bh[ni], acc[mi][ni], 0,0,0);
                acc[mi][ni] = __builtin_amdgcn_mfma_f32_16x16x32_bf16(ah[mi], bl[ni], acc[mi][ni], 0,0,0);
                acc[mi][ni] = __builtin_amdgcn_mfma_f32_16x16x32_bf16(al[mi], bh[ni], acc[mi][ni], 0,0,0);
            }
        __syncthreads();
    }
#pragma unroll
    for(int mi=0;mi<MI_;mi++)
#pragma unroll
        for(int ni=0;ni<NI_;ni++){
            int col = n0 + wn0 + ni*16 + lr;
#pragma unroll
            for(int r=0;r<4;r++){
                int row = m0 + wm0 + mi*16 + quad4 + r;
                C[(size_t)row*N + col] = acc[mi][ni][r];
            }
        }
}

// ---- conv+SiLU | xproj MFMA (6 waves: 3 n-tiles x 2 K-halves) | dtproj ----
__global__ void __launch_bounds__(512) k_convxp2(
    const float* __restrict__ xz, const float* __restrict__ cw, const float* __restrict__ cb,
    const unsigned short* __restrict__ Bhi, const unsigned short* __restrict__ Blo,
    const float* __restrict__ dtW, const float* __restrict__ dtbias,
    float* __restrict__ xh, float* __restrict__ bc, float* __restrict__ dtO)
{
    __shared__ unsigned short sAh[16*520], sAl[16*520];
    __shared__ float dls[16*17];
    __shared__ float pacc[6][16*17];

    int tid = threadIdx.x;
    int wave = tid >> 6, lane = tid & 63;
    int lr = lane & 15, kq = (lane>>4)*8, quad4 = (lane>>4)*4;
    int m0 = blockIdx.x * LCH;
    int d  = tid;

    // phase A: conv + SiLU
    float xv[19];
    {
        int rbase = m0 - 3;
        bool mask0 = ((m0 & (T_-1)) == 0);
#pragma unroll
        for(int j=0;j<19;j++)
            xv[j] = (mask0 && j<3) ? 0.f : xz[(size_t)(rbase+j)*DX + d];
    }
    float4 w4 = *(const float4*)(cw + d*4);
    float bias = cb[d];
#pragma unroll
    for(int t=0;t<16;t++){
        float a = bias + w4.x*xv[t] + w4.y*xv[t+1] + w4.z*xv[t+2] + w4.w*xv[t+3];
        float v = a * sigmoidf_(a);
        xh[(size_t)(m0+t)*DI + d] = v;
        unsigned short hh = f2bf(v);
        sAh[t*520 + d] = hh;
        sAl[t*520 + d] = f2bf(v - bf2f(hh));
    }
    float wr_[16]; ld16(dtW + (size_t)d*16, wr_);
    float bsv = dtbias[d];
    __syncthreads();

    // phase B: xproj MFMA; wave w<6: n-tile w%3, K-half w/3 (8 ks each)
    if(wave < 6){
        int ni = wave % 3, kh = wave / 3;
        f32x4 acc = {0.f,0.f,0.f,0.f};
#pragma unroll
        for(int k8=0;k8<8;k8++){
            int ks = kh*8 + k8;
            int ao = lr*520 + ks*32 + kq;
            bf16x8 ah = *(const bf16x8*)(&sAh[ao]);
            bf16x8 al = *(const bf16x8*)(&sAl[ao]);
            size_t wo = (size_t)(ni*16 + lr)*DI + ks*32 + kq;
            bf16x8 bh = *(const bf16x8*)(Bhi + wo);
            bf16x8 bl = *(const bf16x8*)(Blo + wo);
            acc = __builtin_amdgcn_mfma_f32_16x16x32_bf16(ah, bh, acc, 0,0,0);
            acc = __builtin_amdgcn_mfma_f32_16x16x32_bf16(ah, bl, acc, 0,0,0);
            acc = __builtin_amdgcn_mfma_f32_16x16x32_bf16(al, bh, acc, 0,0,0);
        }
#pragma unroll
        for(int r=0;r<4;r++) pacc[wave][(quad4+r)*17 + lr] = acc[r];
    }
    __syncthreads();
    // combine K-halves; route tile0 -> dls, tile1/2 -> bc
    if(tid < 768){
        int ni = tid >> 8, e = tid & 255;
        int row = e >> 4, col = e & 15;
        float v = pacc[ni][row*17 + col] + pacc[ni+3][row*17 + col];
        if(ni == 0)      dls[row*17 + col] = v;
        else if(ni == 1) bc[(size_t)(m0+row)*32 + col] = v;
        else             bc[(size_t)(m0+row)*32 + 16 + col] = v;
    }
    __syncthreads();

    // phase C: dtproj + softplus
#pragma unroll
    for(int t=0;t<16;t++){
        float acc2 = bsv;
#pragma unroll
        for(int r=0;r<16;r++) acc2 += dls[t*17 + r]*wr_[r];
        float sp = fmaxf(acc2,0.f) + log1pf(__expf(-fabsf(acc2)));
        dtO[(size_t)(m0+t)*DI + d] = sp;
    }
}

// ---- scan pass-1 ----
__global__ void __launch_bounds__(256) k_scan1(const float* __restrict__ dt,
    const float* __restrict__ xh, const float* __restrict__ bc,
    const float* __restrict__ A_log, float* __restrict__ S, float* __restrict__ sdt){
    int d = blockIdx.x*256 + threadIdx.x;
    int c = blockIdx.y, b = blockIdx.z;
    float a_[16]; ld16(A_log + (size_t)d*16, a_);
#pragma unroll
    for(int n=0;n<16;n++) a_[n] = -__expf(a_[n]);
    float st_[16];
#pragma unroll
    for(int n=0;n<16;n++) st_[n] = 0.f;
    float sd = 0.f;
    int base = b*T_ + c*LCH;
#pragma unroll 4
    for(int t=0;t<LCH;t++){
        int bt = base + t;
        float dtv = dt[(size_t)bt*DI + d];
        float xhv = xh[(size_t)bt*DI + d];
        float bv[16]; ld16(bc + (size_t)bt*32, bv);
        float dx = dtv*xhv;
        sd += dtv;
#pragma unroll
        for(int n=0;n<16;n++) st_[n] = __expf(dtv*a_[n])*st_[n] + dx*bv[n];
    }
    st16(S + (((size_t)b*NC_ + c)*DI + d)*16, st_);
    sdt[((size_t)b*NC_ + c)*DI + d] = sd;
}

// ---- pass 2: inter-chunk scan ----
__global__ void k_scan2(const float* __restrict__ S, const float* __restrict__ sdt,
                        const float* __restrict__ A_log, float* __restrict__ Hinit){
    int g = blockIdx.x*256 + threadIdx.x;
    int b = g >> 13;
    int dn = g & 8191;
    int d = dn >> 4;
    float a = -__expf(A_log[dn]);
    float H = 0.f;
    for(int c=0;c<NC_;c++){
        size_t o = ((size_t)(b*NC_ + c))*8192 + dn;
        Hinit[o] = H;
        float sd = sdt[(size_t)(b*NC_ + c)*DI + d];
        H = __expf(sd*a)*H + S[o];
    }
}

// ---- scan pass-3: replay + gate, packed Y out ----
__global__ void __launch_bounds__(256) k_scan3(
    const float* __restrict__ dt, const float* __restrict__ xh, const float* __restrict__ xz,
    const float* __restrict__ bc, const float* __restrict__ A_log, const float* __restrict__ Dpar,
    const float* __restrict__ Hinit, unsigned* __restrict__ Y)
{
    __shared__ float sbc[16*36];
    int tid = threadIdx.x;
    int c = blockIdx.y, b = blockIdx.z;
    int m0 = b*T_ + c*LCH;
    if(tid < 128){
        int t = tid >> 3, s = tid & 7;
        *(float4*)(&sbc[t*36 + s*4]) = *(const float4*)(bc + (size_t)(m0+t)*32 + s*4);
    }
    __syncthreads();
    int d = blockIdx.x*256 + tid;
    float a_[16]; ld16(A_log + (size_t)d*16, a_);
#pragma unroll
    for(int n=0;n<16;n++) a_[n] = -__expf(a_[n]);
    float st_[16]; ld16(Hinit + (((size_t)b*NC_ + c)*DI + d)*16, st_);
    float Dp = Dpar[d];
#pragma unroll 4
    for(int t=0;t<LCH;t++){
        int bt = m0 + t;
        float dtv = dt[(size_t)bt*DI + d];
        float xhv = xh[(size_t)bt*DI + d];
        float bv[16]; ld16(&sbc[t*36], bv);
        float cv[16]; ld16(&sbc[t*36 + 16], cv);
        float dx = dtv*xhv;
        float y = 0.f;
#pragma unroll
        for(int n=0;n<16;n++){
            st_[n] = __expf(dtv*a_[n])*st_[n] + dx*bv[n];
            y += st_[n]*cv[n];
        }
        float zv = xz[(size_t)bt*DX + DI + d];
        y += Dp*xhv;
        y = y * zv * sigmoidf_(zv);
        unsigned short hh = f2bf(y);
        unsigned short ll = f2bf(y - bf2f(hh));
        Y[(size_t)bt*DI + d] = (unsigned)hh | ((unsigned)ll << 16);
    }
}

// out[bt] = dot(h[bt, :256], out_W)
__global__ void k_outw(const float* __restrict__ h, const float* __restrict__ ow,
                       float* __restrict__ out){
    int wv = threadIdx.x >> 6, lane = threadIdx.x & 63;
    int bt = blockIdx.x*4 + wv;
    float4 v = ((const float4*)(h + (size_t)bt*DM))[lane];
    float4 w = ((const float4*)ow)[lane];
    float s = v.x*w.x + v.y*w.y + v.z*w.z + v.w*w.w;
#pragma unroll
    for(int m=1;m<64;m<<=1) s += __shfl_xor(s,m);
    if(lane==0) out[bt] = s;
}

extern "C" void kernel_launch(void* const* d_in, const int* in_sizes, int n_in,
                              void* d_out, int out_size, void* d_ws, size_t ws_size,
                              hipStream_t stream){
    const float* x_src    = (const float*)d_in[0];
    const float* in_W     = (const float*)d_in[2];
    const float* norm_w   = (const float*)d_in[3];
    const float* norm_b   = (const float*)d_in[4];
    const float* inproj_W = (const float*)d_in[5];
    const float* conv_w   = (const float*)d_in[6];
    const float* conv_b   = (const float*)d_in[7];
    const float* xproj_W  = (const float*)d_in[8];
    const float* dtproj_W = (const float*)d_in[9];
    const float* dtproj_b = (const float*)d_in[10];
    const float* A_log    = (const float*)d_in[11];
    const float* D_param  = (const float*)d_in[12];
    const float* outproj_W= (const float*)d_in[13];
    const float* out_W    = (const float*)d_in[14];

    float* ws  = (float*)d_ws;
    float* h    = ws;                        // BT*DM
    float* res  = h    + (size_t)BT_*DM;     // BT*DM
    float* xz   = res  + (size_t)BT_*DM;     // BT*DX
    float* xh   = xz   + (size_t)BT_*DX;     // BT*DI
    float* bcb  = xh   + (size_t)BT_*DI;     // BT*32
    float* dtb  = bcb  + (size_t)BT_*32;     // BT*DI
    float* sdtb = dtb  + (size_t)BT_*DI;     // B*NC*DI
    float* Sbuf = sdtb + (size_t)B_*NC_*DI;  // B*NC*DI*16
    float* Hbuf = Sbuf + (size_t)B_*NC_*DI*DS_;
    unsigned short* us = (unsigned short*)(Hbuf + (size_t)B_*NC_*DI*DS_);
    unsigned short* WhiIn  = us;                                  // NL*DX*DM
    unsigned short* WloIn  = WhiIn  + (size_t)NL*DX*DM;
    unsigned short* WhiOut = WloIn  + (size_t)NL*DX*DM;           // NL*DM*DI
    unsigned short* WloOut = WhiOut + (size_t)NL*DM*DI;
    unsigned short* WhiXp  = WloOut + (size_t)NL*DM*DI;           // NL*NO*DI
    unsigned short* WloXp  = WhiXp  + (size_t)NL*NO_*DI;
    unsigned short* hnhi   = WloXp  + (size_t)NL*NO_*DI;          // BT*DM
    unsigned short* hnlo   = hnhi   + (size_t)BT_*DM;
    unsigned*       ybuf   = (unsigned*)(hnlo + (size_t)BT_*DM);  // BT*DI

    k_cvtW<<<(NL*DX*DM/4 + 255)/256, 256, 0, stream>>>(inproj_W,  WhiIn,  WloIn,  NL*DX*DM/4);
    k_cvtW<<<(NL*DM*DI/4 + 255)/256, 256, 0, stream>>>(outproj_W, WhiOut, WloOut, NL*DM*DI/4);
    k_cvtW<<<(NL*NO_*DI/4 + 255)/256, 256, 0, stream>>>(xproj_W, WhiXp, WloXp, NL*NO_*DI/4);
    k_ingemm<<<BT_*DM/256, 256, 0, stream>>>(x_src, in_W, h);
    for(int i=0;i<NL;i++){
        k_resln<<<BT_/4, 256, 0, stream>>>(h, res, hnhi, hnlo, norm_w + i*DM, norm_b + i*DM, i>0 ? 1 : 0);
        k_gemm_bf3<128,128><<<dim3(DX/128, BT_/128), 256, 0, stream>>>(
            hnhi, hnlo, WhiIn + (size_t)i*DX*DM, WloIn + (size_t)i*DX*DM, xz, BT_, DX, DM);
        k_convxp2<<<BT_/LCH, 512, 0, stream>>>(xz, conv_w + i*DI*4, conv_b + i*DI,
            WhiXp + (size_t)i*NO_*DI, WloXp + (size_t)i*NO_*DI,
            dtproj_W + (size_t)i*DI*DR_, dtproj_b + i*DI, xh, bcb, dtb);
        k_scan1<<<dim3(2, NC_, B_), 256, 0, stream>>>(dtb, xh, bcb,
            A_log + (size_t)i*DI*DS_, Sbuf, sdtb);
        k_scan2<<<B_*DI*DS_/256, 256, 0, stream>>>(Sbuf, sdtb, A_log + (size_t)i*DI*DS_, Hbuf);
        k_scan3<<<dim3(2, NC_, B_), 256, 0, stream>>>(dtb, xh, xz, bcb, A_log + (size_t)i*DI*DS_,
            D_param + i*DI, Hbuf, ybuf);
        k_gemm_pk<128,64><<<dim3(DM/64, BT_/128), 256, 0, stream>>>(
            ybuf, WhiOut + (size_t)i*DM*DI, WloOut + (size_t)i*DM*DI, h, BT_, DM, DI);
    }
    k_outw<<<BT_/4, 256, 0, stream>>>(h, out_W, (float*)d_out);
}

// Round 13
// 611.714 us; speedup vs baseline: 1.1302x; 1.0231x over previous
//
#include <hip/hip_runtime.h>

#define B_   4
#define T_   2048
#define BT_  8192
#define INL  15
#define DM   256
#define DI   512
#define DX   1024
#define DS_  16
#define DR_  16
#define NO_  48
#define NL   4
#define NC_  128
#define LCH  16

typedef short bf16x8 __attribute__((ext_vector_type(8)));
typedef float f32x4  __attribute__((ext_vector_type(4)));

__device__ __forceinline__ float sigmoidf_(float x){ return 1.f/(1.f+__expf(-x)); }

__device__ __forceinline__ unsigned short f2bf(float x){
    union { float f; unsigned u; } v; v.f = x;
    unsigned r = (v.u + 0x7FFFu + ((v.u >> 16) & 1u)) >> 16;
    return (unsigned short)r;
}
__device__ __forceinline__ float bf2f(unsigned short h){
    union { unsigned u; float f; } v; v.u = ((unsigned)h) << 16;
    return v.f;
}

__device__ __forceinline__ void ld16(const float* __restrict__ p, float* v){
    const float4* q = (const float4*)p;
    float4 x0=q[0],x1=q[1],x2=q[2],x3=q[3];
    v[0]=x0.x; v[1]=x0.y; v[2]=x0.z; v[3]=x0.w;
    v[4]=x1.x; v[5]=x1.y; v[6]=x1.z; v[7]=x1.w;
    v[8]=x2.x; v[9]=x2.y; v[10]=x2.z; v[11]=x2.w;
    v[12]=x3.x; v[13]=x3.y; v[14]=x3.z; v[15]=x3.w;
}
__device__ __forceinline__ void st16(float* __restrict__ p, const float* v){
    float4* q = (float4*)p;
    q[0] = make_float4(v[0],v[1],v[2],v[3]);
    q[1] = make_float4(v[4],v[5],v[6],v[7]);
    q[2] = make_float4(v[8],v[9],v[10],v[11]);
    q[3] = make_float4(v[12],v[13],v[14],v[15]);
}

// convert three fp32 arrays -> bf16 hi/lo splits in one launch
__global__ void k_cvtW3(const float* __restrict__ W0, unsigned short* __restrict__ h0,
                        unsigned short* __restrict__ l0, int n0,
                        const float* __restrict__ W1, unsigned short* __restrict__ h1,
                        unsigned short* __restrict__ l1, int n1,
                        const float* __restrict__ W2, unsigned short* __restrict__ h2,
                        unsigned short* __restrict__ l2, int n2){
    int g = blockIdx.x*256 + threadIdx.x;
    const float* W; unsigned short *hi, *lo; int idx;
    if(g < n0){ W = W0; hi = h0; lo = l0; idx = g; }
    else if(g < n0+n1){ W = W1; hi = h1; lo = l1; idx = g - n0; }
    else if(g < n0+n1+n2){ W = W2; hi = h2; lo = l2; idx = g - n0 - n1; }
    else return;
    float4 v = ((const float4*)W)[idx];
    ushort4 h, l;
    h.x = f2bf(v.x); l.x = f2bf(v.x - bf2f(h.x));
    h.y = f2bf(v.y); l.y = f2bf(v.y - bf2f(h.y));
    h.z = f2bf(v.z); l.z = f2bf(v.z - bf2f(h.z));
    h.w = f2bf(v.w); l.w = f2bf(v.w - bf2f(h.w));
    ((ushort4*)hi)[idx] = h;
    ((ushort4*)lo)[idx] = l;
}

// fused input GEMM (K=15) + layer-0 LN: res = x@inW^T; hn = LN(res)*w+b -> bf16 hi/lo
__global__ void k_inln(const float* __restrict__ x, const float* __restrict__ W,
                       float* __restrict__ res,
                       unsigned short* __restrict__ hnhi, unsigned short* __restrict__ hnlo,
                       const float* __restrict__ w, const float* __restrict__ b){
    int wv = threadIdx.x >> 6, lane = threadIdx.x & 63;
    int bt = blockIdx.x*4 + wv;
    const float* xr = x + bt*INL;
    float xl[INL];
#pragma unroll
    for(int k=0;k<INL;k++) xl[k] = xr[k];
    float4 v;
    float* vv = (float*)&v;
#pragma unroll
    for(int j=0;j<4;j++){
        int m = lane*4 + j;
        const float* wr = W + m*INL;
        float acc = 0.f;
#pragma unroll
        for(int k=0;k<INL;k++) acc += xl[k]*wr[k];
        vv[j] = acc;
    }
    ((float4*)(res + (size_t)bt*DM))[lane] = v;
    float s  = v.x+v.y+v.z+v.w;
    float ss = v.x*v.x+v.y*v.y+v.z*v.z+v.w*v.w;
#pragma unroll
    for(int m=1;m<64;m<<=1){ s += __shfl_xor(s,m); ss += __shfl_xor(ss,m); }
    float mean = s*(1.f/DM);
    float var  = ss*(1.f/DM) - mean*mean;
    float inv  = rsqrtf(var + 1e-5f);
    float4 wt = ((const float4*)w)[lane];
    float4 bs = ((const float4*)b)[lane];
    float4 o;
    o.x = (v.x-mean)*inv*wt.x + bs.x;
    o.y = (v.y-mean)*inv*wt.y + bs.y;
    o.z = (v.z-mean)*inv*wt.z + bs.z;
    o.w = (v.w-mean)*inv*wt.w + bs.w;
    ushort4 hh, ll;
    hh.x = f2bf(o.x); ll.x = f2bf(o.x - bf2f(hh.x));
    hh.y = f2bf(o.y); ll.y = f2bf(o.y - bf2f(hh.y));
    hh.z = f2bf(o.z); ll.z = f2bf(o.z - bf2f(hh.z));
    hh.w = f2bf(o.w); ll.w = f2bf(o.w - bf2f(hh.w));
    ((ushort4*)(hnhi + (size_t)bt*DM))[lane] = hh;
    ((ushort4*)(hnlo + (size_t)bt*DM))[lane] = ll;
}

// res = h (+ res_prev); hn = LN(res)*w+b -> bf16 hi/lo  (layers 1..3)
__global__ void k_resln(const float* __restrict__ h, float* __restrict__ res,
                        unsigned short* __restrict__ hnhi, unsigned short* __restrict__ hnlo,
                        const float* __restrict__ w, const float* __restrict__ b, int addRes){
    int wv = threadIdx.x >> 6, lane = threadIdx.x & 63;
    int bt = blockIdx.x*4 + wv;
    float4 v = ((const float4*)(h + (size_t)bt*DM))[lane];
    if(addRes){
        float4 r = ((const float4*)(res + (size_t)bt*DM))[lane];
        v.x+=r.x; v.y+=r.y; v.z+=r.z; v.w+=r.w;
    }
    ((float4*)(res + (size_t)bt*DM))[lane] = v;
    float s  = v.x+v.y+v.z+v.w;
    float ss = v.x*v.x+v.y*v.y+v.z*v.z+v.w*v.w;
#pragma unroll
    for(int m=1;m<64;m<<=1){ s += __shfl_xor(s,m); ss += __shfl_xor(ss,m); }
    float mean = s*(1.f/DM);
    float var  = ss*(1.f/DM) - mean*mean;
    float inv  = rsqrtf(var + 1e-5f);
    float4 wt = ((const float4*)w)[lane];
    float4 bs = ((const float4*)b)[lane];
    float4 o;
    o.x = (v.x-mean)*inv*wt.x + bs.x;
    o.y = (v.y-mean)*inv*wt.y + bs.y;
    o.z = (v.z-mean)*inv*wt.z + bs.z;
    o.w = (v.w-mean)*inv*wt.w + bs.w;
    ushort4 hh, ll;
    hh.x = f2bf(o.x); ll.x = f2bf(o.x - bf2f(hh.x));
    hh.y = f2bf(o.y); ll.y = f2bf(o.y - bf2f(hh.y));
    hh.z = f2bf(o.z); ll.z = f2bf(o.z - bf2f(hh.z));
    hh.w = f2bf(o.w); ll.w = f2bf(o.w - bf2f(hh.w));
    ((ushort4*)(hnhi + (size_t)bt*DM))[lane] = hh;
    ((ushort4*)(hnlo + (size_t)bt*DM))[lane] = ll;
}

// C[M][N] = A[M][K] @ Bw[N][K]^T via bf16 MFMA, hi/lo 3-term split (inproj)
template<int BM,int BN>
__global__ void __launch_bounds__(256) k_gemm_bf3(
    const unsigned short* __restrict__ Ahi, const unsigned short* __restrict__ Alo,
    const unsigned short* __restrict__ Bhi, const unsigned short* __restrict__ Blo,
    float* __restrict__ C, int M, int N, int K)
{
    constexpr int LDP = 40;
    constexpr int WM = BM/2, WN = BN/2;
    constexpr int MI_ = WM/16, NI_ = WN/16;
    __shared__ unsigned short sAh[BM*LDP], sAl[BM*LDP], sBh[BN*LDP], sBl[BN*LDP];
    int tid  = threadIdx.x;
    int wave = tid >> 6, lane = tid & 63;
    int wm0  = (wave >> 1) * WM, wn0 = (wave & 1) * WN;
    int m0   = blockIdx.y * BM, n0 = blockIdx.x * BN;
    int lr   = lane & 15;
    int kq   = (lane >> 4) * 8;
    int quad4 = (lane >> 4) * 4;

    f32x4 acc[MI_][NI_];
#pragma unroll
    for(int i=0;i<MI_;i++)
#pragma unroll
        for(int j=0;j<NI_;j++) acc[i][j] = (f32x4){0.f,0.f,0.f,0.f};

    for(int k0=0;k0<K;k0+=32){
#pragma unroll
        for(int i=tid;i<BM*4;i+=256){
            int r = i>>2, cg = (i&3)*8;
            size_t go = (size_t)(m0+r)*K + k0 + cg;
            *(float4*)(&sAh[r*LDP + cg]) = *(const float4*)(Ahi + go);
            *(float4*)(&sAl[r*LDP + cg]) = *(const float4*)(Alo + go);
        }
#pragma unroll
        for(int i=tid;i<BN*4;i+=256){
            int r = i>>2, cg = (i&3)*8;
            size_t go = (size_t)(n0+r)*K + k0 + cg;
            *(float4*)(&sBh[r*LDP + cg]) = *(const float4*)(Bhi + go);
            *(float4*)(&sBl[r*LDP + cg]) = *(const float4*)(Blo + go);
        }
        __syncthreads();
        bf16x8 ah[MI_], al[MI_], bh[NI_], bl[NI_];
#pragma unroll
        for(int mi=0;mi<MI_;mi++){
            int ro = (wm0 + mi*16 + lr)*LDP + kq;
            ah[mi] = *(const bf16x8*)(&sAh[ro]);
            al[mi] = *(const bf16x8*)(&sAl[ro]);
        }
#pragma unroll
        for(int ni=0;ni<NI_;ni++){
            int ro = (wn0 + ni*16 + lr)*LDP + kq;
            bh[ni] = *(const bf16x8*)(&sBh[ro]);
            bl[ni] = *(const bf16x8*)(&sBl[ro]);
        }
#pragma unroll
        for(int mi=0;mi<MI_;mi++)
#pragma unroll
            for(int ni=0;ni<NI_;ni++){
                acc[mi][ni] = __builtin_amdgcn_mfma_f32_16x16x32_bf16(ah[mi], bh[ni], acc[mi][ni], 0,0,0);
                acc[mi][ni] = __builtin_amdgcn_mfma_f32_16x16x32_bf16(ah[mi], bl[ni], acc[mi][ni], 0,0,0);
                acc[mi][ni] = __builtin_amdgcn_mfma_f32_16x16x32_bf16(al[mi], bh[ni], acc[mi][ni], 0,0,0);
            }
        __syncthreads();
    }
#pragma unroll
    for(int mi=0;mi<MI_;mi++)
#pragma unroll
        for(int ni=0;ni<NI_;ni++){
            int col = n0 + wn0 + ni*16 + lr;
#pragma unroll
            for(int r=0;r<4;r++){
                int row = m0 + wm0 + mi*16 + quad4 + r;
                C[(size_t)row*N + col] = acc[mi][ni][r];
            }
        }
}

// ---- outproj: same GEMM but A rows are packed (hi | lo<<16) uints from scan3 ----
template<int BM,int BN>
__global__ void __launch_bounds__(256) k_gemm_pk(
    const unsigned* __restrict__ Apk,
    const unsigned short* __restrict__ Bhi, const unsigned short* __restrict__ Blo,
    float* __restrict__ C, int M, int N, int K)
{
    constexpr int LDP = 40;
    constexpr int WM = BM/2, WN = BN/2;
    constexpr int MI_ = WM/16, NI_ = WN/16;
    __shared__ unsigned short sAh[BM*LDP], sAl[BM*LDP], sBh[BN*LDP], sBl[BN*LDP];
    int tid  = threadIdx.x;
    int wave = tid >> 6, lane = tid & 63;
    int wm0  = (wave >> 1) * WM, wn0 = (wave & 1) * WN;
    int m0   = blockIdx.y * BM, n0 = blockIdx.x * BN;
    int lr   = lane & 15;
    int kq   = (lane >> 4) * 8;
    int quad4 = (lane >> 4) * 4;

    f32x4 acc[MI_][NI_];
#pragma unroll
    for(int i=0;i<MI_;i++)
#pragma unroll
        for(int j=0;j<NI_;j++) acc[i][j] = (f32x4){0.f,0.f,0.f,0.f};

    for(int k0=0;k0<K;k0+=32){
#pragma unroll
        for(int i=tid;i<BM*2;i+=256){
            int r = i>>1, hf = (i&1)*16;
            const uint4* yp = (const uint4*)(Apk + (size_t)(m0+r)*K + k0 + hf);
#pragma unroll
            for(int q=0;q<4;q++){
                uint4 p = yp[q];
                ushort4 H, L;
                H.x=(unsigned short)p.x;  L.x=(unsigned short)(p.x>>16);
                H.y=(unsigned short)p.y;  L.y=(unsigned short)(p.y>>16);
                H.z=(unsigned short)p.z;  L.z=(unsigned short)(p.z>>16);
                H.w=(unsigned short)p.w;  L.w=(unsigned short)(p.w>>16);
                *(ushort4*)(&sAh[r*LDP + hf + q*4]) = H;
                *(ushort4*)(&sAl[r*LDP + hf + q*4]) = L;
            }
        }
#pragma unroll
        for(int i=tid;i<BN*4;i+=256){
            int r = i>>2, cg = (i&3)*8;
            size_t go = (size_t)(n0+r)*K + k0 + cg;
            *(float4*)(&sBh[r*LDP + cg]) = *(const float4*)(Bhi + go);
            *(float4*)(&sBl[r*LDP + cg]) = *(const float4*)(Blo + go);
        }
        __syncthreads();
        bf16x8 ah[MI_], al[MI_], bh[NI_], bl[NI_];
#pragma unroll
        for(int mi=0;mi<MI_;mi++){
            int ro = (wm0 + mi*16 + lr)*LDP + kq;
            ah[mi] = *(const bf16x8*)(&sAh[ro]);
            al[mi] = *(const bf16x8*)(&sAl[ro]);
        }
#pragma unroll
        for(int ni=0;ni<NI_;ni++){
            int ro = (wn0 + ni*16 + lr)*LDP + kq;
            bh[ni] = *(const bf16x8*)(&sBh[ro]);
            bl[ni] = *(const bf16x8*)(&sBl[ro]);
        }
#pragma unroll
        for(int mi=0;mi<MI_;mi++)
#pragma unroll
            for(int ni=0;ni<NI_;ni++){
                acc[mi][ni] = __builtin_amdgcn_mfma_f32_16x16x32_bf16(ah[mi], bh[ni], acc[mi][ni], 0,0,0);
                acc[mi][ni] = __builtin_amdgcn_mfma_f32_16x16x32_bf16(ah[mi], bl[ni], acc[mi][ni], 0,0,0);
                acc[mi][ni] = __builtin_amdgcn_mfma_f32_16x16x32_bf16(al[mi], bh[ni], acc[mi][ni], 0,0,0);
            }
        __syncthreads();
    }
#pragma unroll
    for(int mi=0;mi<MI_;mi++)
#pragma unroll
        for(int ni=0;ni<NI_;ni++){
            int col = n0 + wn0 + ni*16 + lr;
#pragma unroll
            for(int r=0;r<4;r++){
                int row = m0 + wm0 + mi*16 + quad4 + r;
                C[(size_t)row*N + col] = acc[mi][ni][r];
            }
        }
}

// ---- conv+SiLU | xproj MFMA (3 waves) | dtproj ----
__global__ void __launch_bounds__(512) k_convxp2(
    const float* __restrict__ xz, const float* __restrict__ cw, const float* __restrict__ cb,
    const unsigned short* __restrict__ Bhi, const unsigned short* __restrict__ Blo,
    const float* __restrict__ dtW, const float* __restrict__ dtbias,
    float* __restrict__ xh, float* __restrict__ bc, float* __restrict__ dtO)
{
    __shared__ unsigned short sAh[16*520], sAl[16*520];
    __shared__ float dls[16*17];

    int tid = threadIdx.x;
    int wave = tid >> 6, lane = tid & 63;
    int lr = lane & 15, kq = (lane>>4)*8, quad4 = (lane>>4)*4;
    int m0 = blockIdx.x * LCH;
    int d  = tid;

    // phase A: conv + SiLU
    float xv[19];
    {
        int rbase = m0 - 3;
        bool mask0 = ((m0 & (T_-1)) == 0);
#pragma unroll
        for(int j=0;j<19;j++)
            xv[j] = (mask0 && j<3) ? 0.f : xz[(size_t)(rbase+j)*DX + d];
    }
    float4 w4 = *(const float4*)(cw + d*4);
    float bias = cb[d];
#pragma unroll
    for(int t=0;t<16;t++){
        float a = bias + w4.x*xv[t] + w4.y*xv[t+1] + w4.z*xv[t+2] + w4.w*xv[t+3];
        float v = a * sigmoidf_(a);
        xh[(size_t)(m0+t)*DI + d] = v;
        unsigned short hh = f2bf(v);
        sAh[t*520 + d] = hh;
        sAl[t*520 + d] = f2bf(v - bf2f(hh));
    }
    float wr_[16]; ld16(dtW + (size_t)d*16, wr_);
    float bsv = dtbias[d];
    __syncthreads();

    // phase B: xproj MFMA, waves 0-2 = n-tiles, B streamed from L2
    f32x4 acc = {0.f,0.f,0.f,0.f};
    if(wave < 3){
#pragma unroll 4
        for(int ks=0;ks<16;ks++){
            int ao = lr*520 + ks*32 + kq;
            bf16x8 ah = *(const bf16x8*)(&sAh[ao]);
            bf16x8 al = *(const bf16x8*)(&sAl[ao]);
            size_t wo = (size_t)(wave*16 + lr)*DI + ks*32 + kq;
            bf16x8 bh = *(const bf16x8*)(Bhi + wo);
            bf16x8 bl = *(const bf16x8*)(Blo + wo);
            acc = __builtin_amdgcn_mfma_f32_16x16x32_bf16(ah, bh, acc, 0,0,0);
            acc = __builtin_amdgcn_mfma_f32_16x16x32_bf16(ah, bl, acc, 0,0,0);
            acc = __builtin_amdgcn_mfma_f32_16x16x32_bf16(al, bh, acc, 0,0,0);
        }
        if(wave == 0){
#pragma unroll
            for(int r=0;r<4;r++) dls[(quad4+r)*17 + lr] = acc[r];
        } else if(wave == 1){
#pragma unroll
            for(int r=0;r<4;r++) bc[(size_t)(m0+quad4+r)*32 + lr] = acc[r];
        } else {
#pragma unroll
            for(int r=0;r<4;r++) bc[(size_t)(m0+quad4+r)*32 + 16 + lr] = acc[r];
        }
    }
    __syncthreads();

    // phase C: dtproj + softplus
#pragma unroll
    for(int t=0;t<16;t++){
        float acc2 = bsv;
#pragma unroll
        for(int r=0;r<16;r++) acc2 += dls[t*17 + r]*wr_[r];
        float sp = fmaxf(acc2,0.f) + log1pf(__expf(-fabsf(acc2)));
        dtO[(size_t)(m0+t)*DI + d] = sp;
    }
}

// ---- scan pass-1 ----
__global__ void __launch_bounds__(256) k_scan1(const float* __restrict__ dt,
    const float* __restrict__ xh, const float* __restrict__ bc,
    const float* __restrict__ A_log, float* __restrict__ S, float* __restrict__ sdt){
    int d = blockIdx.x*256 + threadIdx.x;
    int c = blockIdx.y, b = blockIdx.z;
    float a_[16]; ld16(A_log + (size_t)d*16, a_);
#pragma unroll
    for(int n=0;n<16;n++) a_[n] = -__expf(a_[n]);
    float st_[16];
#pragma unroll
    for(int n=0;n<16;n++) st_[n] = 0.f;
    float sd = 0.f;
    int base = b*T_ + c*LCH;
#pragma unroll 4
    for(int t=0;t<LCH;t++){
        int bt = base + t;
        float dtv = dt[(size_t)bt*DI + d];
        float xhv = xh[(size_t)bt*DI + d];
        float bv[16]; ld16(bc + (size_t)bt*32, bv);
        float dx = dtv*xhv;
        sd += dtv;
#pragma unroll
        for(int n=0;n<16;n++) st_[n] = __expf(dtv*a_[n])*st_[n] + dx*bv[n];
    }
    st16(S + (((size_t)b*NC_ + c)*DI + d)*16, st_);
    sdt[((size_t)b*NC_ + c)*DI + d] = sd;
}

// ---- pass 2: inter-chunk scan ----
__global__ void k_scan2(const float* __restrict__ S, const float* __restrict__ sdt,
                        const float* __restrict__ A_log, float* __restrict__ Hinit){
    int g = blockIdx.x*256 + threadIdx.x;
    int b = g >> 13;
    int dn = g & 8191;
    int d = dn >> 4;
    float a = -__expf(A_log[dn]);
    float H = 0.f;
    for(int c=0;c<NC_;c++){
        size_t o = ((size_t)(b*NC_ + c))*8192 + dn;
        Hinit[o] = H;
        float sd = sdt[(size_t)(b*NC_ + c)*DI + d];
        H = __expf(sd*a)*H + S[o];
    }
}

// ---- scan pass-3: replay + gate, packed Y out ----
__global__ void __launch_bounds__(256) k_scan3(
    const float* __restrict__ dt, const float* __restrict__ xh, const float* __restrict__ xz,
    const float* __restrict__ bc, const float* __restrict__ A_log, const float* __restrict__ Dpar,
    const float* __restrict__ Hinit, unsigned* __restrict__ Y)
{
    __shared__ float sbc[16*36];
    int tid = threadIdx.x;
    int c = blockIdx.y, b = blockIdx.z;
    int m0 = b*T_ + c*LCH;
    if(tid < 128){
        int t = tid >> 3, s = tid & 7;
        *(float4*)(&sbc[t*36 + s*4]) = *(const float4*)(bc + (size_t)(m0+t)*32 + s*4);
    }
    __syncthreads();
    int d = blockIdx.x*256 + tid;
    float a_[16]; ld16(A_log + (size_t)d*16, a_);
#pragma unroll
    for(int n=0;n<16;n++) a_[n] = -__expf(a_[n]);
    float st_[16]; ld16(Hinit + (((size_t)b*NC_ + c)*DI + d)*16, st_);
    float Dp = Dpar[d];
#pragma unroll 4
    for(int t=0;t<LCH;t++){
        int bt = m0 + t;
        float dtv = dt[(size_t)bt*DI + d];
        float xhv = xh[(size_t)bt*DI + d];
        float bv[16]; ld16(&sbc[t*36], bv);
        float cv[16]; ld16(&sbc[t*36 + 16], cv);
        float dx = dtv*xhv;
        float y = 0.f;
#pragma unroll
        for(int n=0;n<16;n++){
            st_[n] = __expf(dtv*a_[n])*st_[n] + dx*bv[n];
            y += st_[n]*cv[n];
        }
        float zv = xz[(size_t)bt*DX + DI + d];
        y += Dp*xhv;
        y = y * zv * sigmoidf_(zv);
        unsigned short hh = f2bf(y);
        unsigned short ll = f2bf(y - bf2f(hh));
        Y[(size_t)bt*DI + d] = (unsigned)hh | ((unsigned)ll << 16);
    }
}

// out[bt] = dot(h[bt, :256], out_W)
__global__ void k_outw(const float* __restrict__ h, const float* __restrict__ ow,
                       float* __restrict__ out){
    int wv = threadIdx.x >> 6, lane = threadIdx.x & 63;
    int bt = blockIdx.x*4 + wv;
    float4 v = ((const float4*)(h + (size_t)bt*DM))[lane];
    float4 w = ((const float4*)ow)[lane];
    float s = v.x*w.x + v.y*w.y + v.z*w.z + v.w*w.w;
#pragma unroll
    for(int m=1;m<64;m<<=1) s += __shfl_xor(s,m);
    if(lane==0) out[bt] = s;
}

extern "C" void kernel_launch(void* const* d_in, const int* in_sizes, int n_in,
                              void* d_out, int out_size, void* d_ws, size_t ws_size,
                              hipStream_t stream){
    const float* x_src    = (const float*)d_in[0];
    const float* in_W     = (const float*)d_in[2];
    const float* norm_w   = (const float*)d_in[3];
    const float* norm_b   = (const float*)d_in[4];
    const float* inproj_W = (const float*)d_in[5];
    const float* conv_w   = (const float*)d_in[6];
    const float* conv_b   = (const float*)d_in[7];
    const float* xproj_W  = (const float*)d_in[8];
    const float* dtproj_W = (const float*)d_in[9];
    const float* dtproj_b = (const float*)d_in[10];
    const float* A_log    = (const float*)d_in[11];
    const float* D_param  = (const float*)d_in[12];
    const float* outproj_W= (const float*)d_in[13];
    const float* out_W    = (const float*)d_in[14];

    float* ws  = (float*)d_ws;
    float* h    = ws;                        // BT*DM
    float* res  = h    + (size_t)BT_*DM;     // BT*DM
    float* xz   = res  + (size_t)BT_*DM;     // BT*DX
    float* xh   = xz   + (size_t)BT_*DX;     // BT*DI
    float* bcb  = xh   + (size_t)BT_*DI;     // BT*32
    float* dtb  = bcb  + (size_t)BT_*32;     // BT*DI
    float* sdtb = dtb  + (size_t)BT_*DI;     // B*NC*DI
    float* Sbuf = sdtb + (size_t)B_*NC_*DI;  // B*NC*DI*16
    float* Hbuf = Sbuf + (size_t)B_*NC_*DI*DS_;
    unsigned short* us = (unsigned short*)(Hbuf + (size_t)B_*NC_*DI*DS_);
    unsigned short* WhiIn  = us;                                  // NL*DX*DM
    unsigned short* WloIn  = WhiIn  + (size_t)NL*DX*DM;
    unsigned short* WhiOut = WloIn  + (size_t)NL*DX*DM;           // NL*DM*DI
    unsigned short* WloOut = WhiOut + (size_t)NL*DM*DI;
    unsigned short* WhiXp  = WloOut + (size_t)NL*DM*DI;           // NL*NO*DI
    unsigned short* WloXp  = WhiXp  + (size_t)NL*NO_*DI;
    unsigned short* hnhi   = WloXp  + (size_t)NL*NO_*DI;          // BT*DM
    unsigned short* hnlo   = hnhi   + (size_t)BT_*DM;
    unsigned*       ybuf   = (unsigned*)(hnlo + (size_t)BT_*DM);  // BT*DI

    int n0 = NL*DX*DM/4, n1 = NL*DM*DI/4, n2 = NL*NO_*DI/4;
    k_cvtW3<<<(n0+n1+n2 + 255)/256, 256, 0, stream>>>(
        inproj_W,  WhiIn,  WloIn,  n0,
        outproj_W, WhiOut, WloOut, n1,
        xproj_W,   WhiXp,  WloXp,  n2);
    k_inln<<<BT_/4, 256, 0, stream>>>(x_src, in_W, res, hnhi, hnlo, norm_w, norm_b);
    for(int i=0;i<NL;i++){
        if(i > 0)
            k_resln<<<BT_/4, 256, 0, stream>>>(h, res, hnhi, hnlo, norm_w + i*DM, norm_b + i*DM, 1);
        k_gemm_bf3<128,128><<<dim3(DX/128, BT_/128), 256, 0, stream>>>(
            hnhi, hnlo, WhiIn + (size_t)i*DX*DM, WloIn + (size_t)i*DX*DM, xz, BT_, DX, DM);
        k_convxp2<<<BT_/LCH, 512, 0, stream>>>(xz, conv_w + i*DI*4, conv_b + i*DI,
            WhiXp + (size_t)i*NO_*DI, WloXp + (size_t)i*NO_*DI,
            dtproj_W + (size_t)i*DI*DR_, dtproj_b + i*DI, xh, bcb, dtb);
        k_scan1<<<dim3(2, NC_, B_), 256, 0, stream>>>(dtb, xh, bcb,
            A_log + (size_t)i*DI*DS_, Sbuf, sdtb);
        k_scan2<<<B_*DI*DS_/256, 256, 0, stream>>>(Sbuf, sdtb, A_log + (size_t)i*DI*DS_, Hbuf);
        k_scan3<<<dim3(2, NC_, B_), 256, 0, stream>>>(dtb, xh, xz, bcb, A_log + (size_t)i*DI*DS_,
            D_param + i*DI, Hbuf, ybuf);
        k_gemm_pk<128,64><<<dim3(DM/64, BT_/128), 256, 0, stream>>>(
            ybuf, WhiOut + (size_t)i*DM*DI, WloOut + (size_t)i*DM*DI, h, BT_, DM, DI);
    }
    k_outw<<<BT_/4, 256, 0, stream>>>(h, out_W, (float*)d_out);
}